// Round 4
// baseline (428.969 us; speedup 1.0000x reference)
//
#include <hip/hip_runtime.h>

typedef unsigned short u16;
typedef short bf16x8 __attribute__((ext_vector_type(8)));
typedef float f32x4 __attribute__((ext_vector_type(4)));

#define MFMA16(a,b,c) __builtin_amdgcn_mfma_f32_16x16x32_bf16((a),(b),(c),0,0,0)
#define NEGHUGE (-1.0e30f)

__device__ __forceinline__ u16 f2b(float f){
  union { float f; unsigned int i; } v; v.f = f;
  unsigned int r = v.i + 0x7FFFu + ((v.i>>16)&1u);
  return (u16)(r>>16);
}

union BfPack { u16 h[8]; bf16x8 v; uint4 u; };

__device__ __forceinline__ uint4 pack8u(const float* __restrict__ p){
  float4 a = *(const float4*)p;
  float4 b = *(const float4*)(p + 4);
  BfPack r;
  r.h[0]=f2b(a.x); r.h[1]=f2b(a.y); r.h[2]=f2b(a.z); r.h[3]=f2b(a.w);
  r.h[4]=f2b(b.x); r.h[5]=f2b(b.y); r.h[6]=f2b(b.z); r.h[7]=f2b(b.w);
  return r.u;
}

// async 16B global -> LDS; LDS dest is wave-uniform base + lane*16
__device__ __forceinline__ void gld_lds16(const u16* g, u16* l){
  __builtin_amdgcn_global_load_lds(
      (const __attribute__((address_space(1))) unsigned int*)g,
      (__attribute__((address_space(3))) unsigned int*)l, 16, 0, 0);
}

// ---------------- kernel 1: f32 -> bf16 convert + weight fragment-packing ----
// x: linear bf16 (2,408,448 units of 8 floats).
// wqkv/wout: packed into MFMA B-fragment order: unit u = (nf*12 + k)*64 + l
// holds W[nf*16 + (l&15)][k*32 + (l>>4)*8 .. +8] so a GEMM B-load is one
// contiguous 1KB span per (frag, k-iter).  wqkv: 55,296 u, wout: 18,432 u.
__global__ __launch_bounds__(256) void k_convert(
    const float* __restrict__ x, const float* __restrict__ wqkv,
    const float* __restrict__ wout,
    u16* __restrict__ xb, u16* __restrict__ wqkvp, u16* __restrict__ woutp)
{
  int idx = (int)blockIdx.x * 256 + threadIdx.x;   // 9696*256 = 2,482,176
  if (idx < 2408448) {
    *(uint4*)(xb + (size_t)idx*8) = pack8u(x + (size_t)idx*8);
  } else if (idx < 2463744) {
    int u = idx - 2408448;
    int nf = u / 768, rem = u - nf*768, k = rem >> 6, l = rem & 63;
    const float* src = wqkv + (size_t)(nf*16 + (l & 15))*384 + k*32 + (l >> 4)*8;
    *(uint4*)(wqkvp + (size_t)u*8) = pack8u(src);
  } else {
    int u = idx - 2463744;
    int nf = u / 768, rem = u - nf*768, k = rem >> 6, l = rem & 63;
    const float* src = wout + (size_t)(nf*16 + (l & 15))*384 + k*32 + (l >> 4)*8;
    *(uint4*)(woutp + (size_t)u*8) = pack8u(src);
  }
}

// ---------------- kernel 2: fused QKV-GEMM + window attention + projection ---
// 1 block = 1 window (16 batches x 64 windows = 1024 blocks), 6 waves.
// Wave wv handles heads {wv, 6+wv} in 2 sequential passes.
// Phases: stage x-window -> At (48KB, chunk-XOR swizzled, async) | per pass:
// QKV GEMM (acc 4x6) -> Q|K|V^T LDS slots -> QK^T -> softmax (P overwrites
// Q|K slot) -> PV (attn-out held in regs) | barrier | attn-out -> At (bf16)
// | barrier | projection GEMM + bias -> global f32 at rolled(+3) coords.
// qkvs/attnb intermediates eliminated entirely.
__global__ __launch_bounds__(384, 2) void k_fused(
    const u16* __restrict__ xb, const u16* __restrict__ wqkvp,
    const u16* __restrict__ woutp, const float* __restrict__ bout,
    const float* __restrict__ relt, float* __restrict__ out)
{
  __shared__ u16 At[64*384];        // 49152 B: x-tile, later attn-out tile
  __shared__ u16 QKs[6][49*64];     // 37632 B: per-wave Q|K, later P (swz)
  __shared__ u16 Vts[6][32*64];     // 24576 B: per-wave V^T (swz, zero-pad)
  __shared__ float relb[6][169];    //  4056 B: per-wave rel-pos column

  const int tid = threadIdx.x;
  const int wv = tid >> 6, lane = tid & 63, quad = lane >> 4, l16 = lane & 15;
  const int blk = (int)blockIdx.x;                 // 1024 blocks
  const int b = blk >> 6, win = blk & 63, hb = win >> 3, wb = win & 7;

  u16* qk = &QKs[wv][0];
  u16* vt = &Vts[wv][0];

  // zero own V^T slot (pads pos 49..63 stay zero through both passes)
  #pragma unroll
  for (int i = 0; i < 4; ++i)
    *(uint4*)(vt + (i*64 + lane)*8) = uint4{0,0,0,0};

  // stage x-window rows -> At: 64 rows (pos 49..63 = clamped row-48 copies,
  // finite, outputs discarded); source chunk XOR-swizzled with (row&7)
  #pragma unroll
  for (int i = 0; i < 8; ++i) {
    const int u = wv*512 + i*64 + lane;            // 16B unit 0..3071
    const int r = u / 48, c = u - r*48;
    const int cl = c ^ (r & 7);
    const int pos = r < 49 ? r : 48;
    const int py = pos / 7, px = pos - py*7;
    int hh = hb*7 + py + 3; if (hh >= 56) hh -= 56;
    int ww = wb*7 + px + 3; if (ww >= 56) ww -= 56;
    gld_lds16(xb + (size_t)((b*56 + hh)*56 + ww)*384 + cl*8,
              At + (size_t)(wv*512 + i*64)*8);
  }
  __syncthreads();   // At ready (drains vmcnt)

  f32x4 oacc[2][4][2];   // attn-out for both head passes

  #pragma unroll
  for (int pass = 0; pass < 2; ++pass) {
    const int head = pass*6 + wv;

    // rel-pos column for this head (own-wave LDS, no barrier needed)
    for (int i = lane; i < 169; i += 64) relb[wv][i] = relt[i*12 + head];

    // ---- QKV GEMM: 64 window rows x {Q,K,V}x32 cols of this head
    f32x4 acc[4][6];
    #pragma unroll
    for (int mi = 0; mi < 4; ++mi)
      #pragma unroll
      for (int f = 0; f < 6; ++f) acc[mi][f] = f32x4{0.f,0.f,0.f,0.f};

    #pragma unroll
    for (int k = 0; k < 12; ++k) {
      bf16x8 a[4], bb[6];
      const int ck = ((k*4 + quad) ^ (l16 & 7)) << 3;
      #pragma unroll
      for (int mi = 0; mi < 4; ++mi)
        a[mi] = *(const bf16x8*)(At + (mi*16 + l16)*384 + ck);
      #pragma unroll
      for (int f = 0; f < 6; ++f) {
        const int nf = (f >> 1)*24 + head*2 + (f & 1);
        bb[f] = *(const bf16x8*)(wqkvp + ((size_t)(nf*12 + k)*64 + lane)*8);
      }
      #pragma unroll
      for (int mi = 0; mi < 4; ++mi)
        #pragma unroll
        for (int f = 0; f < 6; ++f)
          acc[mi][f] = MFMA16(a[mi], bb[f], acc[mi][f]);
    }

    // ---- epilogue -> per-wave slots (swizzled); only pos < 49 stored
    #pragma unroll
    for (int mi = 0; mi < 4; ++mi)
      #pragma unroll
      for (int r = 0; r < 4; ++r) {
        const int pos = mi*16 + quad*4 + r;
        if (pos < 49) {
          #pragma unroll
          for (int f = 0; f < 6; ++f) {
            const u16 val = f2b(acc[mi][f][r]);
            if (f < 4) {          // Q chunks 0..3, K chunks 4..7
              const int c = (f >> 1)*4 + (f & 1)*2 + (l16 >> 3);
              qk[pos*64 + ((c ^ (pos & 7)) << 3) + (l16 & 7)] = val;
            } else {              // V transposed: vt[d][pos], pos-chunk swz
              const int d = (f & 1)*16 + l16;
              vt[d*64 + (((pos >> 3) ^ (d & 7)) << 3) + (pos & 7)] = val;
            }
          }
        }
      }

    // ---- QK^T (A: row=pos q, B: col=pos key; clamp pad rows to 48)
    bf16x8 aq[4], bk[4];
    #pragma unroll
    for (int mt = 0; mt < 4; ++mt) {
      int p2 = mt*16 + l16; if (p2 > 48) p2 = 48;
      aq[mt] = *(const bf16x8*)(qk + p2*64 + ((quad ^ (p2 & 7)) << 3));
    }
    #pragma unroll
    for (int n = 0; n < 4; ++n) {
      int kp = n*16 + l16; if (kp > 48) kp = 48;
      bk[n] = *(const bf16x8*)(qk + kp*64 + (((4 + quad) ^ (kp & 7)) << 3));
    }
    f32x4 sc[4][4];
    #pragma unroll
    for (int mt = 0; mt < 4; ++mt)
      #pragma unroll
      for (int n = 0; n < 4; ++n) {
        f32x4 z = {0.f,0.f,0.f,0.f};
        sc[mt][n] = MFMA16(aq[mt], bk[n], z);
      }

    // ---- bias + mask + softmax; P overwrites Q|K slot (q < 49 rows only)
    #pragma unroll
    for (int mt = 0; mt < 4; ++mt)
      #pragma unroll
      for (int r = 0; r < 4; ++r) {
        const int q = mt*16 + quad*4 + r;
        const int qy = q / 7, qx = q - qy*7;
        #pragma unroll
        for (int n = 0; n < 4; ++n) {
          const int key = n*16 + l16;
          float s = sc[mt][n][r] * 0.17677669529663687f;   // 1/sqrt(32)
          if (key < 49 && q < 49) {
            const int ky = key / 7, kx = key - ky*7;
            s += relb[wv][(ky - qy + 6)*13 + (kx - qx + 6)];
            if (hb == 7 && ((qy >= 4) != (ky >= 4))) s = NEGHUGE;  // UL mask
          } else {
            s = NEGHUGE;
          }
          sc[mt][n][r] = s;
        }
        float mx = fmaxf(fmaxf(sc[mt][0][r], sc[mt][1][r]),
                         fmaxf(sc[mt][2][r], sc[mt][3][r]));
        mx = fmaxf(mx, __shfl_xor(mx, 1));
        mx = fmaxf(mx, __shfl_xor(mx, 2));
        mx = fmaxf(mx, __shfl_xor(mx, 4));
        mx = fmaxf(mx, __shfl_xor(mx, 8));
        float sum = 0.f;
        #pragma unroll
        for (int n = 0; n < 4; ++n) {
          float p = exp2f((sc[mt][n][r] - mx) * 1.4426950408889634f);
          sc[mt][n][r] = p; sum += p;
        }
        sum += __shfl_xor(sum, 1);
        sum += __shfl_xor(sum, 2);
        sum += __shfl_xor(sum, 4);
        sum += __shfl_xor(sum, 8);
        const float rinv = 1.0f / sum;
        if (q < 49) {
          #pragma unroll
          for (int n = 0; n < 4; ++n)
            qk[q*64 + (((n*2 + (l16 >> 3)) ^ (q & 7)) << 3) + (l16 & 7)] =
                f2b(sc[mt][n][r] * rinv);
        }
      }

    // ---- PV -> registers (keys 49..63: P=0 and V^T pad=0)
    #pragma unroll
    for (int mt = 0; mt < 4; ++mt) {
      int rp = mt*16 + l16; if (rp > 48) rp = 48;
      const bf16x8 ap0 = *(const bf16x8*)(qk + rp*64 + ((quad ^ (rp & 7)) << 3));
      const bf16x8 ap1 = *(const bf16x8*)(qk + rp*64 + (((4+quad) ^ (rp & 7)) << 3));
      #pragma unroll
      for (int n2 = 0; n2 < 2; ++n2) {
        const int d = n2*16 + l16;
        const bf16x8 bv0 = *(const bf16x8*)(vt + d*64 + ((quad ^ (d & 7)) << 3));
        const bf16x8 bv1 = *(const bf16x8*)(vt + d*64 + (((4+quad) ^ (d & 7)) << 3));
        f32x4 o = {0.f,0.f,0.f,0.f};
        o = MFMA16(ap0, bv0, o);
        o = MFMA16(ap1, bv1, o);
        oacc[pass][mt][n2] = o;
      }
    }
  }  // pass

  // ---- attn-out (both heads) -> At as bf16 (pad rows keep finite x data)
  __syncthreads();   // all waves done reading At
  #pragma unroll
  for (int pass = 0; pass < 2; ++pass) {
    const int head = pass*6 + wv;
    #pragma unroll
    for (int mt = 0; mt < 4; ++mt)
      #pragma unroll
      for (int n2 = 0; n2 < 2; ++n2)
        #pragma unroll
        for (int r = 0; r < 4; ++r) {
          const int q = mt*16 + quad*4 + r;
          if (q < 49) {
            const int c = head*4 + n2*2 + (l16 >> 3);
            At[q*384 + ((c ^ (q & 7)) << 3) + (l16 & 7)] =
                f2b(oacc[pass][mt][n2][r]);
          }
        }
  }
  __syncthreads();

  // ---- projection: out = attn @ w_out^T + b_out, stored at rolled coords
  f32x4 pacc[4][4];
  #pragma unroll
  for (int mi = 0; mi < 4; ++mi)
    #pragma unroll
    for (int j = 0; j < 4; ++j) pacc[mi][j] = f32x4{0.f,0.f,0.f,0.f};

  #pragma unroll
  for (int k = 0; k < 12; ++k) {
    bf16x8 a[4], bb[4];
    const int ck = ((k*4 + quad) ^ (l16 & 7)) << 3;
    #pragma unroll
    for (int mi = 0; mi < 4; ++mi)
      a[mi] = *(const bf16x8*)(At + (mi*16 + l16)*384 + ck);
    #pragma unroll
    for (int j = 0; j < 4; ++j) {
      const int nf = wv*4 + j;
      bb[j] = *(const bf16x8*)(woutp + ((size_t)(nf*12 + k)*64 + lane)*8);
    }
    #pragma unroll
    for (int mi = 0; mi < 4; ++mi)
      #pragma unroll
      for (int j = 0; j < 4; ++j)
        pacc[mi][j] = MFMA16(a[mi], bb[j], pacc[mi][j]);
  }

  float bias[4];
  #pragma unroll
  for (int j = 0; j < 4; ++j) bias[j] = bout[wv*64 + j*16 + l16];

  #pragma unroll
  for (int mi = 0; mi < 4; ++mi)
    #pragma unroll
    for (int r = 0; r < 4; ++r) {
      const int q = mi*16 + quad*4 + r;
      if (q < 49) {
        const int py = q / 7, px = q - py*7;
        int hh = hb*7 + py + 3; if (hh >= 56) hh -= 56;   // inverse roll
        int ww = wb*7 + px + 3; if (ww >= 56) ww -= 56;
        float* dst = out + (size_t)((b*56 + hh)*56 + ww)*384 + wv*64;
        #pragma unroll
        for (int j = 0; j < 4; ++j)
          dst[j*16 + l16] = pacc[mi][j][r] + bias[j];
      }
    }
}

extern "C" void kernel_launch(void* const* d_in, const int* in_sizes, int n_in,
                              void* d_out, int out_size, void* d_ws, size_t ws_size,
                              hipStream_t stream) {
  const float* x    = (const float*)d_in[0];
  const float* wqkv = (const float*)d_in[1];
  const float* wout = (const float*)d_in[2];
  const float* bout = (const float*)d_in[3];
  const float* relt = (const float*)d_in[4];

  char* ws = (char*)d_ws;
  u16* xb    = (u16*)(ws);                        // 38,535,168 B
  u16* wqkvp = (u16*)(ws + 38535168);             //    884,736 B
  u16* woutp = (u16*)(ws + 39419904);             //    294,912 B
  float* outp = (float*)d_out;

  k_convert<<<9696, 256, 0, stream>>>(x, wqkv, wout, xb, wqkvp, woutp);
  k_fused<<<1024, 384, 0, stream>>>(xb, wqkvp, woutp, bout, relt, outp);
}

// Round 5
// 404.656 us; speedup vs baseline: 1.0601x; 1.0601x over previous
//
#include <hip/hip_runtime.h>

typedef unsigned short u16;
typedef short bf16x8 __attribute__((ext_vector_type(8)));
typedef float f32x4 __attribute__((ext_vector_type(4)));

#define MFMA16(a,b,c) __builtin_amdgcn_mfma_f32_16x16x32_bf16((a),(b),(c),0,0,0)
#define NEGHUGE (-1.0e30f)

__device__ __forceinline__ u16 f2b(float f){
  union { float f; unsigned int i; } v; v.f = f;
  unsigned int r = v.i + 0x7FFFu + ((v.i>>16)&1u);
  return (u16)(r>>16);
}

union BfPack { u16 h[8]; bf16x8 v; uint4 u; };

__device__ __forceinline__ uint4 pack8u(const float* __restrict__ p){
  float4 a = *(const float4*)p;
  float4 b = *(const float4*)(p + 4);
  BfPack r;
  r.h[0]=f2b(a.x); r.h[1]=f2b(a.y); r.h[2]=f2b(a.z); r.h[3]=f2b(a.w);
  r.h[4]=f2b(b.x); r.h[5]=f2b(b.y); r.h[6]=f2b(b.z); r.h[7]=f2b(b.w);
  return r.u;
}

// async 16B global -> LDS; LDS dest is wave-uniform base + lane*16
__device__ __forceinline__ void gld_lds16(const u16* g, u16* l){
  __builtin_amdgcn_global_load_lds(
      (const __attribute__((address_space(1))) unsigned int*)g,
      (__attribute__((address_space(3))) unsigned int*)l, 16, 0, 0);
}

// ---------------- kernel 1: f32 -> bf16 convert + weight fragment-packing ----
// x: linear bf16 (2,408,448 units of 8 floats).
// wqkv/wout: packed into MFMA B-fragment order: unit u = (nf*12 + k)*64 + l
// holds W[nf*16 + (l&15)][k*32 + (l>>4)*8 .. +8] so a GEMM B-load is one
// contiguous 1KB span per (frag, k-iter).  wqkv: 55,296 u, wout: 18,432 u.
__global__ __launch_bounds__(256) void k_convert(
    const float* __restrict__ x, const float* __restrict__ wqkv,
    const float* __restrict__ wout,
    u16* __restrict__ xb, u16* __restrict__ wqkvp, u16* __restrict__ woutp)
{
  int idx = (int)blockIdx.x * 256 + threadIdx.x;   // 9696*256 = 2,482,176
  if (idx < 2408448) {
    *(uint4*)(xb + (size_t)idx*8) = pack8u(x + (size_t)idx*8);
  } else if (idx < 2463744) {
    int u = idx - 2408448;
    int nf = u / 768, rem = u - nf*768, k = rem >> 6, l = rem & 63;
    const float* src = wqkv + (size_t)(nf*16 + (l & 15))*384 + k*32 + (l >> 4)*8;
    *(uint4*)(wqkvp + (size_t)u*8) = pack8u(src);
  } else {
    int u = idx - 2463744;
    int nf = u / 768, rem = u - nf*768, k = rem >> 6, l = rem & 63;
    const float* src = wout + (size_t)(nf*16 + (l & 15))*384 + k*32 + (l >> 4)*8;
    *(uint4*)(woutp + (size_t)u*8) = pack8u(src);
  }
}

// ---------------- kernel 2: fused QKV-GEMM + window attention + projection ---
// 1 block = 1 window (1024 blocks), 6 waves; wave wv does heads {wv, 6+wv}.
// Per pass: QKV GEMM (acc 4x6) -> Q|K (per-wave LDS) + V^T (per-wave LDS) ->
// QK^T -> softmax (P overwrites Q|K) -> PV -> Os[head] (bf16, A-frag layout).
// NO cross-pass register state (spill fix). Projection reads A-fragments
// straight from Os (k-iter == head). 2 barriers total. LDS 153,048 B.
__global__ __launch_bounds__(384, 1) void k_fused(
    const u16* __restrict__ xb, const u16* __restrict__ wqkvp,
    const u16* __restrict__ woutp, const float* __restrict__ bout,
    const float* __restrict__ relt, float* __restrict__ out)
{
  __shared__ u16 At[64*384];        // 49152 B: x-window tile (chunk-XOR swz)
  __shared__ u16 QKs[6][49*64];     // 37632 B: per-wave Q|K, then P
  __shared__ u16 Vts[6][32*64];     // 24576 B: per-wave V^T (zero-padded pos)
  __shared__ u16 Os[12][49*32];     // 37632 B: per-head attn-out (bf16)
  __shared__ float relb[6][169];    //  4056 B: per-wave rel-pos column

  const int tid = threadIdx.x;
  const int wv = tid >> 6, lane = tid & 63, quad = lane >> 4, l16 = lane & 15;
  const int blk = (int)blockIdx.x;                 // 1024 blocks
  const int b = blk >> 6, win = blk & 63, hb = win >> 3, wb = win & 7;

  u16* qk = &QKs[wv][0];
  u16* vt = &Vts[wv][0];

  // zero own V^T slot (pads pos 49..63 stay zero through both passes)
  #pragma unroll
  for (int i = 0; i < 4; ++i)
    *(uint4*)(vt + (i*64 + lane)*8) = uint4{0,0,0,0};

  // stage x-window rows -> At: 64 rows (49..63 clamped row-48 copies);
  // source chunk XOR-swizzled with (row&7), LDS dest linear
  #pragma unroll
  for (int i = 0; i < 8; ++i) {
    const int u = wv*512 + i*64 + lane;            // 16B unit 0..3071
    const int r = u / 48, c = u - r*48;
    const int cl = c ^ (r & 7);
    const int pos = r < 49 ? r : 48;
    const int py = pos / 7, px = pos - py*7;
    int hh = hb*7 + py + 3; if (hh >= 56) hh -= 56;
    int ww = wb*7 + px + 3; if (ww >= 56) ww -= 56;
    gld_lds16(xb + (size_t)((b*56 + hh)*56 + ww)*384 + cl*8,
              At + (size_t)(wv*512 + i*64)*8);
  }
  __syncthreads();   // At ready (drains vmcnt)

  #pragma unroll
  for (int pass = 0; pass < 2; ++pass) {
    const int head = pass*6 + wv;

    // rel-pos column for this head (own-wave slot, no barrier needed)
    for (int i = lane; i < 169; i += 64) relb[wv][i] = relt[i*12 + head];

    // ---- QKV GEMM: 64 window rows x {Q,K,V}x32 cols of this head
    f32x4 acc[4][6];
    #pragma unroll
    for (int mi = 0; mi < 4; ++mi)
      #pragma unroll
      for (int f = 0; f < 6; ++f) acc[mi][f] = f32x4{0.f,0.f,0.f,0.f};

    #pragma unroll
    for (int k = 0; k < 12; ++k) {
      bf16x8 a[4], bb[6];
      const int ck = ((k*4 + quad) ^ (l16 & 7)) << 3;
      #pragma unroll
      for (int mi = 0; mi < 4; ++mi)
        a[mi] = *(const bf16x8*)(At + (mi*16 + l16)*384 + ck);
      #pragma unroll
      for (int f = 0; f < 6; ++f) {
        const int nf = (f >> 1)*24 + head*2 + (f & 1);
        bb[f] = *(const bf16x8*)(wqkvp + ((size_t)(nf*12 + k)*64 + lane)*8);
      }
      #pragma unroll
      for (int mi = 0; mi < 4; ++mi)
        #pragma unroll
        for (int f = 0; f < 6; ++f)
          acc[mi][f] = MFMA16(a[mi], bb[f], acc[mi][f]);
    }

    // ---- epilogue -> per-wave slots; quad-safe swizzle ((pos>>1)&7)
    #pragma unroll
    for (int mi = 0; mi < 4; ++mi)
      #pragma unroll
      for (int r = 0; r < 4; ++r) {
        const int pos = mi*16 + quad*4 + r;
        if (pos < 49) {
          const int swq = (pos >> 1) & 7;
          #pragma unroll
          for (int f = 0; f < 6; ++f) {
            const u16 val = f2b(acc[mi][f][r]);
            if (f < 4) {          // Q chunks 0..3, K chunks 4..7
              const int c = (f >> 1)*4 + (f & 1)*2 + (l16 >> 3);
              qk[pos*64 + ((c ^ swq) << 3) + (l16 & 7)] = val;
            } else {              // V transposed: vt[d][pos], pos-chunk swz
              const int d = (f & 1)*16 + l16;
              vt[d*64 + (((pos >> 3) ^ (d & 7)) << 3) + (pos & 7)] = val;
            }
          }
        }
      }

    // ---- QK^T (A: row=q pos, B: col=key pos; clamp pad rows to 48)
    bf16x8 aq[4], bk[4];
    #pragma unroll
    for (int mt = 0; mt < 4; ++mt) {
      int p2 = mt*16 + l16; if (p2 > 48) p2 = 48;
      aq[mt] = *(const bf16x8*)(qk + p2*64 + ((quad ^ ((p2 >> 1) & 7)) << 3));
    }
    #pragma unroll
    for (int n = 0; n < 4; ++n) {
      int kp = n*16 + l16; if (kp > 48) kp = 48;
      bk[n] = *(const bf16x8*)(qk + kp*64 + (((4 + quad) ^ ((kp >> 1) & 7)) << 3));
    }
    f32x4 sc[4][4];
    #pragma unroll
    for (int mt = 0; mt < 4; ++mt)
      #pragma unroll
      for (int n = 0; n < 4; ++n) {
        f32x4 z = {0.f,0.f,0.f,0.f};
        sc[mt][n] = MFMA16(aq[mt], bk[n], z);
      }

    // ---- bias + mask + softmax; P overwrites Q|K slot (rows q < 49)
    #pragma unroll
    for (int mt = 0; mt < 4; ++mt)
      #pragma unroll
      for (int r = 0; r < 4; ++r) {
        const int q = mt*16 + quad*4 + r;
        const int qy = q / 7, qx = q - qy*7;
        #pragma unroll
        for (int n = 0; n < 4; ++n) {
          const int key = n*16 + l16;
          float s = sc[mt][n][r] * 0.17677669529663687f;   // 1/sqrt(32)
          if (key < 49 && q < 49) {
            const int ky = key / 7, kx = key - ky*7;
            s += relb[wv][(ky - qy + 6)*13 + (kx - qx + 6)];
            if (hb == 7 && ((qy >= 4) != (ky >= 4))) s = NEGHUGE;  // UL mask
          } else {
            s = NEGHUGE;
          }
          sc[mt][n][r] = s;
        }
        float mx = fmaxf(fmaxf(sc[mt][0][r], sc[mt][1][r]),
                         fmaxf(sc[mt][2][r], sc[mt][3][r]));
        mx = fmaxf(mx, __shfl_xor(mx, 1));
        mx = fmaxf(mx, __shfl_xor(mx, 2));
        mx = fmaxf(mx, __shfl_xor(mx, 4));
        mx = fmaxf(mx, __shfl_xor(mx, 8));
        float sum = 0.f;
        #pragma unroll
        for (int n = 0; n < 4; ++n) {
          float p = exp2f((sc[mt][n][r] - mx) * 1.4426950408889634f);
          sc[mt][n][r] = p; sum += p;
        }
        sum += __shfl_xor(sum, 1);
        sum += __shfl_xor(sum, 2);
        sum += __shfl_xor(sum, 4);
        sum += __shfl_xor(sum, 8);
        const float rinv = 1.0f / sum;
        if (q < 49) {
          const int swq = (q >> 1) & 7;
          #pragma unroll
          for (int n = 0; n < 4; ++n)
            qk[q*64 + (((n*2 + (l16 >> 3)) ^ swq) << 3) + (l16 & 7)] =
                f2b(sc[mt][n][r] * rinv);
        }
      }

    // ---- PV -> Os[head] immediately (no cross-pass registers)
    #pragma unroll
    for (int mt = 0; mt < 4; ++mt) {
      int rp = mt*16 + l16; if (rp > 48) rp = 48;
      const int swp = (rp >> 1) & 7;
      const bf16x8 ap0 = *(const bf16x8*)(qk + rp*64 + ((quad ^ swp) << 3));
      const bf16x8 ap1 = *(const bf16x8*)(qk + rp*64 + (((4+quad) ^ swp) << 3));
      #pragma unroll
      for (int n2 = 0; n2 < 2; ++n2) {
        const int d = n2*16 + l16;
        const bf16x8 bv0 = *(const bf16x8*)(vt + d*64 + ((quad ^ (d & 7)) << 3));
        const bf16x8 bv1 = *(const bf16x8*)(vt + d*64 + (((4+quad) ^ (d & 7)) << 3));
        f32x4 o = {0.f,0.f,0.f,0.f};
        o = MFMA16(ap0, bv0, o);
        o = MFMA16(ap1, bv1, o);
        #pragma unroll
        for (int r = 0; r < 4; ++r) {
          const int q = mt*16 + quad*4 + r;
          if (q < 49) Os[head][q*32 + n2*16 + l16] = f2b(o[r]);
        }
      }
    }
  }  // pass

  __syncthreads();   // all heads' Os complete

  // ---- projection: out = attn @ w_out^T + b_out; A-frags straight from Os
  // k-iter k == head k; rows 49..63 clamped (outputs discarded).
  f32x4 pacc[4][4];
  #pragma unroll
  for (int mi = 0; mi < 4; ++mi)
    #pragma unroll
    for (int j = 0; j < 4; ++j) pacc[mi][j] = f32x4{0.f,0.f,0.f,0.f};

  #pragma unroll
  for (int k = 0; k < 12; ++k) {
    bf16x8 a[4], bb[4];
    #pragma unroll
    for (int mi = 0; mi < 4; ++mi) {
      int row = mi*16 + l16; if (row > 48) row = 48;
      a[mi] = *(const bf16x8*)(&Os[k][row*32 + quad*8]);
    }
    #pragma unroll
    for (int j = 0; j < 4; ++j) {
      const int nf = wv*4 + j;
      bb[j] = *(const bf16x8*)(woutp + ((size_t)(nf*12 + k)*64 + lane)*8);
    }
    #pragma unroll
    for (int mi = 0; mi < 4; ++mi)
      #pragma unroll
      for (int j = 0; j < 4; ++j)
        pacc[mi][j] = MFMA16(a[mi], bb[j], pacc[mi][j]);
  }

  float bias[4];
  #pragma unroll
  for (int j = 0; j < 4; ++j) bias[j] = bout[wv*64 + j*16 + l16];

  #pragma unroll
  for (int mi = 0; mi < 4; ++mi)
    #pragma unroll
    for (int r = 0; r < 4; ++r) {
      const int q = mi*16 + quad*4 + r;
      if (q < 49) {
        const int py = q / 7, px = q - py*7;
        int hh = hb*7 + py + 3; if (hh >= 56) hh -= 56;   // inverse roll
        int ww = wb*7 + px + 3; if (ww >= 56) ww -= 56;
        float* dst = out + (size_t)((b*56 + hh)*56 + ww)*384 + wv*64;
        #pragma unroll
        for (int j = 0; j < 4; ++j)
          dst[j*16 + l16] = pacc[mi][j][r] + bias[j];
      }
    }
}

extern "C" void kernel_launch(void* const* d_in, const int* in_sizes, int n_in,
                              void* d_out, int out_size, void* d_ws, size_t ws_size,
                              hipStream_t stream) {
  const float* x    = (const float*)d_in[0];
  const float* wqkv = (const float*)d_in[1];
  const float* wout = (const float*)d_in[2];
  const float* bout = (const float*)d_in[3];
  const float* relt = (const float*)d_in[4];

  char* ws = (char*)d_ws;
  u16* xb    = (u16*)(ws);                        // 38,535,168 B
  u16* wqkvp = (u16*)(ws + 38535168);             //    884,736 B
  u16* woutp = (u16*)(ws + 39419904);             //    294,912 B
  float* outp = (float*)d_out;

  k_convert<<<9696, 256, 0, stream>>>(x, wqkv, wout, xb, wqkvp, woutp);
  k_fused<<<1024, 384, 0, stream>>>(xb, wqkvp, woutp, bout, relt, outp);
}

// Round 6
// 347.119 us; speedup vs baseline: 1.2358x; 1.1658x over previous
//
#include <hip/hip_runtime.h>

typedef unsigned short u16;
typedef short bf16x8 __attribute__((ext_vector_type(8)));
typedef float f32x4 __attribute__((ext_vector_type(4)));

#define MFMA16(a,b,c) __builtin_amdgcn_mfma_f32_16x16x32_bf16((a),(b),(c),0,0,0)
#define NEGHUGE (-1.0e30f)

__device__ __forceinline__ u16 f2b(float f){
  union { float f; unsigned int i; } v; v.f = f;
  unsigned int r = v.i + 0x7FFFu + ((v.i>>16)&1u);
  return (u16)(r>>16);
}

union BfPack { u16 h[8]; bf16x8 v; uint4 u; };

__device__ __forceinline__ uint4 pack8u(const float* __restrict__ p){
  float4 a = *(const float4*)p;
  float4 b = *(const float4*)(p + 4);
  BfPack r;
  r.h[0]=f2b(a.x); r.h[1]=f2b(a.y); r.h[2]=f2b(a.z); r.h[3]=f2b(a.w);
  r.h[4]=f2b(b.x); r.h[5]=f2b(b.y); r.h[6]=f2b(b.z); r.h[7]=f2b(b.w);
  return r.u;
}

// async 16B global -> LDS; LDS dest is wave-uniform base + lane*16
__device__ __forceinline__ void gld_lds16(const u16* g, u16* l){
  __builtin_amdgcn_global_load_lds(
      (const __attribute__((address_space(1))) unsigned int*)g,
      (__attribute__((address_space(3))) unsigned int*)l, 16, 0, 0);
}

// ---------------- kernel 1: f32 -> bf16 convert + weight fragment-packing ----
// x: linear bf16 (2,408,448 units of 8 floats).
// wqkv/wout: packed into MFMA B-fragment order: unit u = (nf*12 + k)*64 + l
// holds W[nf*16 + (l&15)][k*32 + (l>>4)*8 .. +8].
__global__ __launch_bounds__(256) void k_convert(
    const float* __restrict__ x, const float* __restrict__ wqkv,
    const float* __restrict__ wout,
    u16* __restrict__ xb, u16* __restrict__ wqkvp, u16* __restrict__ woutp)
{
  int idx = (int)blockIdx.x * 256 + threadIdx.x;   // 9696*256 = 2,482,176
  if (idx < 2408448) {
    *(uint4*)(xb + (size_t)idx*8) = pack8u(x + (size_t)idx*8);
  } else if (idx < 2463744) {
    int u = idx - 2408448;
    int nf = u / 768, rem = u - nf*768, k = rem >> 6, l = rem & 63;
    const float* src = wqkv + (size_t)(nf*16 + (l & 15))*384 + k*32 + (l >> 4)*8;
    *(uint4*)(wqkvp + (size_t)u*8) = pack8u(src);
  } else {
    int u = idx - 2463744;
    int nf = u / 768, rem = u - nf*768, k = rem >> 6, l = rem & 63;
    const float* src = wout + (size_t)(nf*16 + (l & 15))*384 + k*32 + (l >> 4)*8;
    *(uint4*)(woutp + (size_t)u*8) = pack8u(src);
  }
}

// ---------------- kernel 2: fused QKV-GEMM + window attention + projection ---
// 1 block = 1 window (1024 blocks), 6 waves; wave wv does heads {wv, 6+wv}
// in 2 SERIAL passes (#pragma unroll 1 + sched_barrier: no cross-pass reg
// inflation).  QKV GEMM per pass split into 2 frag-groups of 3 (acc[4][3])
// to cap register pressure.  Os rows stride-40 u16 (16B-aligned, bank-safe).
// LDS 150,936 B; 2 barriers total.
__global__ __launch_bounds__(384, 1) void k_fused(
    const u16* __restrict__ xb, const u16* __restrict__ wqkvp,
    const u16* __restrict__ woutp, const float* __restrict__ bout,
    const float* __restrict__ relt, float* __restrict__ out)
{
  __shared__ u16 At[49*384];        // 37632 B: x-window tile (chunk-XOR swz)
  __shared__ u16 QKs[6][49*64];     // 37632 B: per-wave Q|K, then P
  __shared__ u16 Vts[6][32*64];     // 24576 B: per-wave V^T (zero-padded pos)
  __shared__ u16 Os[12][49*40];     // 47040 B: per-head attn-out, stride 40
  __shared__ float relb[6][169];    //  4056 B: per-wave rel-pos column

  const int tid = threadIdx.x;
  const int wv = tid >> 6, lane = tid & 63, quad = lane >> 4, l16 = lane & 15;
  const int blk = (int)blockIdx.x;                 // 1024 blocks
  const int b = blk >> 6, win = blk & 63, hb = win >> 3, wb = win & 7;

  u16* qk = &QKs[wv][0];
  u16* vt = &Vts[wv][0];

  // zero own V^T slot (pads pos 49..63 stay zero through both passes)
  #pragma unroll
  for (int i = 0; i < 4; ++i)
    *(uint4*)(vt + (i*64 + lane)*8) = uint4{0,0,0,0};

  // stage x-window -> At: 49 rows x 48 chunks = 2352 16B units;
  // source chunk XOR-swizzled with (row&7), LDS dest linear
  #pragma unroll
  for (int i = 0; i < 7; ++i) {
    const int u = i*384 + tid;
    if (u < 2352) {
      const int r = u / 48, c = u - r*48;
      const int cl = c ^ (r & 7);
      const int py = r / 7, px = r - py*7;
      int hh = hb*7 + py + 3; if (hh >= 56) hh -= 56;
      int ww = wb*7 + px + 3; if (ww >= 56) ww -= 56;
      gld_lds16(xb + (size_t)((b*56 + hh)*56 + ww)*384 + cl*8,
                At + (size_t)(i*384 + (tid & ~63))*8);
    }
  }
  __syncthreads();   // At ready (drains vmcnt)

  #pragma unroll 1
  for (int pass = 0; pass < 2; ++pass) {
    const int head = pass*6 + wv;

    // rel-pos column for this head (own-wave slot, no barrier needed)
    for (int i = lane; i < 169; i += 64) relb[wv][i] = relt[i*12 + head];

    // ---- QKV GEMM in 2 fragment-groups of 3 (caps register pressure)
    #pragma unroll 1
    for (int g = 0; g < 2; ++g) {
      f32x4 acc[4][3];
      #pragma unroll
      for (int mi = 0; mi < 4; ++mi)
        #pragma unroll
        for (int f = 0; f < 3; ++f) acc[mi][f] = f32x4{0.f,0.f,0.f,0.f};

      for (int k = 0; k < 12; ++k) {
        bf16x8 a[4], bb[3];
        #pragma unroll
        for (int mi = 0; mi < 4; ++mi) {
          int row = mi*16 + l16; if (row > 48) row = 48;
          a[mi] = *(const bf16x8*)(At + row*384 +
                                   (((k*4 + quad) ^ (row & 7)) << 3));
        }
        #pragma unroll
        for (int f = 0; f < 3; ++f) {
          const int fg = g*3 + f;
          const int nf = (fg >> 1)*24 + head*2 + (fg & 1);
          bb[f] = *(const bf16x8*)(wqkvp + ((size_t)(nf*12 + k)*64 + lane)*8);
        }
        #pragma unroll
        for (int mi = 0; mi < 4; ++mi)
          #pragma unroll
          for (int f = 0; f < 3; ++f)
            acc[mi][f] = MFMA16(a[mi], bb[f], acc[mi][f]);
      }

      // epilogue for this group -> per-wave slots
      #pragma unroll
      for (int mi = 0; mi < 4; ++mi)
        #pragma unroll
        for (int r = 0; r < 4; ++r) {
          const int pos = mi*16 + quad*4 + r;
          if (pos < 49) {
            const int swq = (pos >> 1) & 7;
            #pragma unroll
            for (int f = 0; f < 3; ++f) {
              const int fg = g*3 + f;
              const u16 val = f2b(acc[mi][f][r]);
              if (fg < 4) {         // Q chunks 0..3, K chunks 4..7
                const int c = (fg >> 1)*4 + (fg & 1)*2 + (l16 >> 3);
                qk[pos*64 + ((c ^ swq) << 3) + (l16 & 7)] = val;
              } else {              // V transposed: vt[d][pos], pos-chunk swz
                const int d = (fg & 1)*16 + l16;
                vt[d*64 + (((pos >> 3) ^ (d & 7)) << 3) + (pos & 7)] = val;
              }
            }
          }
        }
    }

    // ---- QK^T (A: row=q pos, B: col=key pos; clamp pad rows to 48)
    bf16x8 aq[4], bk[4];
    #pragma unroll
    for (int mt = 0; mt < 4; ++mt) {
      int p2 = mt*16 + l16; if (p2 > 48) p2 = 48;
      aq[mt] = *(const bf16x8*)(qk + p2*64 + ((quad ^ ((p2 >> 1) & 7)) << 3));
    }
    #pragma unroll
    for (int n = 0; n < 4; ++n) {
      int kp = n*16 + l16; if (kp > 48) kp = 48;
      bk[n] = *(const bf16x8*)(qk + kp*64 + (((4 + quad) ^ ((kp >> 1) & 7)) << 3));
    }
    f32x4 sc[4][4];
    #pragma unroll
    for (int mt = 0; mt < 4; ++mt)
      #pragma unroll
      for (int n = 0; n < 4; ++n) {
        f32x4 z = {0.f,0.f,0.f,0.f};
        sc[mt][n] = MFMA16(aq[mt], bk[n], z);
      }

    // ---- bias + mask + softmax; P overwrites Q|K slot (rows q < 49)
    #pragma unroll
    for (int mt = 0; mt < 4; ++mt)
      #pragma unroll
      for (int r = 0; r < 4; ++r) {
        const int q = mt*16 + quad*4 + r;
        const int qy = q / 7, qx = q - qy*7;
        #pragma unroll
        for (int n = 0; n < 4; ++n) {
          const int key = n*16 + l16;
          float s = sc[mt][n][r] * 0.17677669529663687f;   // 1/sqrt(32)
          if (key < 49 && q < 49) {
            const int ky = key / 7, kx = key - ky*7;
            s += relb[wv][(ky - qy + 6)*13 + (kx - qx + 6)];
            if (hb == 7 && ((qy >= 4) != (ky >= 4))) s = NEGHUGE;  // UL mask
          } else {
            s = NEGHUGE;
          }
          sc[mt][n][r] = s;
        }
        float mx = fmaxf(fmaxf(sc[mt][0][r], sc[mt][1][r]),
                         fmaxf(sc[mt][2][r], sc[mt][3][r]));
        mx = fmaxf(mx, __shfl_xor(mx, 1));
        mx = fmaxf(mx, __shfl_xor(mx, 2));
        mx = fmaxf(mx, __shfl_xor(mx, 4));
        mx = fmaxf(mx, __shfl_xor(mx, 8));
        float sum = 0.f;
        #pragma unroll
        for (int n = 0; n < 4; ++n) {
          float p = exp2f((sc[mt][n][r] - mx) * 1.4426950408889634f);
          sc[mt][n][r] = p; sum += p;
        }
        sum += __shfl_xor(sum, 1);
        sum += __shfl_xor(sum, 2);
        sum += __shfl_xor(sum, 4);
        sum += __shfl_xor(sum, 8);
        const float rinv = 1.0f / sum;
        if (q < 49) {
          const int swq = (q >> 1) & 7;
          #pragma unroll
          for (int n = 0; n < 4; ++n)
            qk[q*64 + (((n*2 + (l16 >> 3)) ^ swq) << 3) + (l16 & 7)] =
                f2b(sc[mt][n][r] * rinv);
        }
      }

    // ---- PV -> Os[head] immediately (no cross-pass registers)
    #pragma unroll
    for (int mt = 0; mt < 4; ++mt) {
      int rp = mt*16 + l16; if (rp > 48) rp = 48;
      const int swp = (rp >> 1) & 7;
      const bf16x8 ap0 = *(const bf16x8*)(qk + rp*64 + ((quad ^ swp) << 3));
      const bf16x8 ap1 = *(const bf16x8*)(qk + rp*64 + (((4+quad) ^ swp) << 3));
      #pragma unroll
      for (int n2 = 0; n2 < 2; ++n2) {
        const int d = n2*16 + l16;
        const bf16x8 bv0 = *(const bf16x8*)(vt + d*64 + ((quad ^ (d & 7)) << 3));
        const bf16x8 bv1 = *(const bf16x8*)(vt + d*64 + (((4+quad) ^ (d & 7)) << 3));
        f32x4 o = {0.f,0.f,0.f,0.f};
        o = MFMA16(ap0, bv0, o);
        o = MFMA16(ap1, bv1, o);
        #pragma unroll
        for (int r = 0; r < 4; ++r) {
          const int q = mt*16 + quad*4 + r;
          if (q < 49) Os[head][q*40 + n2*16 + l16] = f2b(o[r]);
        }
      }
    }
    __builtin_amdgcn_sched_barrier(0);   // hard wall between passes
  }  // pass

  __syncthreads();   // all heads' Os complete

  // ---- projection: out = attn @ w_out^T + b_out; A-frags straight from Os
  // k-iter k == head k; rows 49..63 clamped (outputs discarded).
  f32x4 pacc[4][4];
  #pragma unroll
  for (int mi = 0; mi < 4; ++mi)
    #pragma unroll
    for (int j = 0; j < 4; ++j) pacc[mi][j] = f32x4{0.f,0.f,0.f,0.f};

  for (int k = 0; k < 12; ++k) {
    bf16x8 a[4], bb[4];
    #pragma unroll
    for (int mi = 0; mi < 4; ++mi) {
      int row = mi*16 + l16; if (row > 48) row = 48;
      a[mi] = *(const bf16x8*)(&Os[k][row*40 + quad*8]);
    }
    #pragma unroll
    for (int j = 0; j < 4; ++j) {
      const int nf = wv*4 + j;
      bb[j] = *(const bf16x8*)(woutp + ((size_t)(nf*12 + k)*64 + lane)*8);
    }
    #pragma unroll
    for (int mi = 0; mi < 4; ++mi)
      #pragma unroll
      for (int j = 0; j < 4; ++j)
        pacc[mi][j] = MFMA16(a[mi], bb[j], pacc[mi][j]);
  }

  float bias[4];
  #pragma unroll
  for (int j = 0; j < 4; ++j) bias[j] = bout[wv*64 + j*16 + l16];

  #pragma unroll
  for (int mi = 0; mi < 4; ++mi)
    #pragma unroll
    for (int r = 0; r < 4; ++r) {
      const int q = mi*16 + quad*4 + r;
      if (q < 49) {
        const int py = q / 7, px = q - py*7;
        int hh = hb*7 + py + 3; if (hh >= 56) hh -= 56;   // inverse roll
        int ww = wb*7 + px + 3; if (ww >= 56) ww -= 56;
        float* dst = out + (size_t)((b*56 + hh)*56 + ww)*384 + wv*64;
        #pragma unroll
        for (int j = 0; j < 4; ++j)
          dst[j*16 + l16] = pacc[mi][j][r] + bias[j];
      }
    }
}

extern "C" void kernel_launch(void* const* d_in, const int* in_sizes, int n_in,
                              void* d_out, int out_size, void* d_ws, size_t ws_size,
                              hipStream_t stream) {
  const float* x    = (const float*)d_in[0];
  const float* wqkv = (const float*)d_in[1];
  const float* wout = (const float*)d_in[2];
  const float* bout = (const float*)d_in[3];
  const float* relt = (const float*)d_in[4];

  char* ws = (char*)d_ws;
  u16* xb    = (u16*)(ws);                        // 38,535,168 B
  u16* wqkvp = (u16*)(ws + 38535168);             //    884,736 B
  u16* woutp = (u16*)(ws + 39419904);             //    294,912 B
  float* outp = (float*)d_out;

  k_convert<<<9696, 256, 0, stream>>>(x, wqkv, wout, xb, wqkvp, woutp);
  k_fused<<<1024, 384, 0, stream>>>(xb, wqkvp, woutp, bout, relt, outp);
}

// Round 7
// 286.970 us; speedup vs baseline: 1.4948x; 1.2096x over previous
//
#include <hip/hip_runtime.h>

typedef unsigned short u16;
typedef short bf16x8 __attribute__((ext_vector_type(8)));
typedef float f32x4 __attribute__((ext_vector_type(4)));

#define MFMA16(a,b,c) __builtin_amdgcn_mfma_f32_16x16x32_bf16((a),(b),(c),0,0,0)
#define NEGHUGE (-1.0e30f)

__device__ __forceinline__ u16 f2b(float f){
  union { float f; unsigned int i; } v; v.f = f;
  unsigned int r = v.i + 0x7FFFu + ((v.i>>16)&1u);
  return (u16)(r>>16);
}

union BfPack { u16 h[8]; bf16x8 v; uint4 u; };

__device__ __forceinline__ uint4 pack8u(const float* __restrict__ p){
  float4 a = *(const float4*)p;
  float4 b = *(const float4*)(p + 4);
  BfPack r;
  r.h[0]=f2b(a.x); r.h[1]=f2b(a.y); r.h[2]=f2b(a.z); r.h[3]=f2b(a.w);
  r.h[4]=f2b(b.x); r.h[5]=f2b(b.y); r.h[6]=f2b(b.z); r.h[7]=f2b(b.w);
  return r.u;
}

// async 16B global -> LDS; LDS dest is wave-uniform base + lane*16
__device__ __forceinline__ void gld_lds16(const u16* g, u16* l){
  __builtin_amdgcn_global_load_lds(
      (const __attribute__((address_space(1))) unsigned int*)g,
      (__attribute__((address_space(3))) unsigned int*)l, 16, 0, 0);
}

// ---------------- kernel 1: f32 -> bf16 convert + weight fragment-packing ----
// x: linear bf16 (2,408,448 units of 8 floats).
// wqkv/wout: packed into MFMA B-fragment order: unit u = (nf*12 + k)*64 + l
// holds W[nf*16 + (l&15)][k*32 + (l>>4)*8 .. +8].
__global__ __launch_bounds__(256) void k_convert(
    const float* __restrict__ x, const float* __restrict__ wqkv,
    const float* __restrict__ wout,
    u16* __restrict__ xb, u16* __restrict__ wqkvp, u16* __restrict__ woutp)
{
  int idx = (int)blockIdx.x * 256 + threadIdx.x;   // 9696*256 = 2,482,176
  if (idx < 2408448) {
    *(uint4*)(xb + (size_t)idx*8) = pack8u(x + (size_t)idx*8);
  } else if (idx < 2463744) {
    int u = idx - 2408448;
    int nf = u / 768, rem = u - nf*768, k = rem >> 6, l = rem & 63;
    const float* src = wqkv + (size_t)(nf*16 + (l & 15))*384 + k*32 + (l >> 4)*8;
    *(uint4*)(wqkvp + (size_t)u*8) = pack8u(src);
  } else {
    int u = idx - 2463744;
    int nf = u / 768, rem = u - nf*768, k = rem >> 6, l = rem & 63;
    const float* src = wout + (size_t)(nf*16 + (l & 15))*384 + k*32 + (l >> 4)*8;
    *(uint4*)(woutp + (size_t)u*8) = pack8u(src);
  }
}

// ---------------- kernel 2: fused QKV + attention + projection ---------------
// 1 block = 1 window (1024 blocks), 12 waves (768 thr), wave wv = head wv.
// Occupancy fix: 3 waves/SIMD via LDS overlays (132,528 B):
//   R1   49,152 B: x-tile At (2352x16B) ...then... Vts[12][32][64] (barrier 2)
//   QKs  75,264 B: per-head Q|K (49x64) -> P -> O (49x40 overlay)
//   relb  8,112 B
// Flow per wave: [stage At coop] b1 | GEMM-A(QK)->qk | GEMM-B(V, acc held)
// b2 | Vt write | QK^T | fixed-shift softmax (no max reduce) -> P | PV -> O
// b3 | projection (k-iter == head, A-frags from O overlay) -> out.
__global__ __launch_bounds__(768, 3) void k_fused(
    const u16* __restrict__ xb, const u16* __restrict__ wqkvp,
    const u16* __restrict__ woutp, const float* __restrict__ bout,
    const float* __restrict__ relt, float* __restrict__ out)
{
  __shared__ u16 R1[64*384];        // 49152 B: At, later Vts[12][2048]
  __shared__ u16 QKs[12][49*64];    // 75264 B: per-head Q|K -> P -> O
  __shared__ float relb[12][169];   //  8112 B

  const int tid = threadIdx.x;
  const int wv = tid >> 6, lane = tid & 63, quad = lane >> 4, l16 = lane & 15;
  const int blk = (int)blockIdx.x;                 // 1024 blocks
  const int b = blk >> 6, win = blk & 63, hb = win >> 3, wb = win & 7;

  u16* qk = &QKs[wv][0];
  u16* At = R1;
  u16* vt = R1 + wv*2048;          // valid only after barrier 2

  // rel-pos column for this head (own slot; consumed only by own wave)
  for (int i = lane; i < 169; i += 64) relb[wv][i] = relt[i*12 + wv];

  // stage x-window -> At: 49 rows x 48 chunks = 2352 16B units, 4 rounds
  #pragma unroll
  for (int i = 0; i < 4; ++i) {
    const int u = i*768 + tid;
    if (u < 2352) {
      const int r = u / 48, c = u - r*48;
      const int cl = c ^ (r & 7);                  // pre-swizzled source chunk
      const int py = r / 7, px = r - py*7;
      int hh = hb*7 + py + 3; if (hh >= 56) hh -= 56;
      int ww = wb*7 + px + 3; if (ww >= 56) ww -= 56;
      gld_lds16(xb + (size_t)((b*56 + hh)*56 + ww)*384 + cl*8,
                At + (size_t)(i*768 + (tid & ~63))*8);
    }
  }
  __syncthreads();   // barrier 1: At ready (drains vmcnt)

  // ---- GEMM group A: Q,K (frags 0..3) for head wv
  f32x4 accA[4][4];
  #pragma unroll
  for (int mi = 0; mi < 4; ++mi)
    #pragma unroll
    for (int f = 0; f < 4; ++f) accA[mi][f] = f32x4{0.f,0.f,0.f,0.f};

  for (int k = 0; k < 12; ++k) {
    bf16x8 a[4], bb[4];
    #pragma unroll
    for (int mi = 0; mi < 4; ++mi) {
      int row = mi*16 + l16; if (row > 48) row = 48;
      a[mi] = *(const bf16x8*)(At + row*384 + (((k*4 + quad) ^ (row & 7)) << 3));
    }
    #pragma unroll
    for (int f = 0; f < 4; ++f) {
      const int nf = (f >> 1)*24 + wv*2 + (f & 1);   // Q: 0..23, K: 24..47
      bb[f] = *(const bf16x8*)(wqkvp + ((size_t)(nf*12 + k)*64 + lane)*8);
    }
    #pragma unroll
    for (int mi = 0; mi < 4; ++mi)
      #pragma unroll
      for (int f = 0; f < 4; ++f)
        accA[mi][f] = MFMA16(a[mi], bb[f], accA[mi][f]);
  }

  // epilogue A -> qk (Q chunks 0..3, K chunks 4..7), quad-safe swizzle
  #pragma unroll
  for (int mi = 0; mi < 4; ++mi)
    #pragma unroll
    for (int r = 0; r < 4; ++r) {
      const int pos = mi*16 + quad*4 + r;
      if (pos < 49) {
        const int swq = (pos >> 1) & 7;
        #pragma unroll
        for (int f = 0; f < 4; ++f) {
          const int c = (f >> 1)*4 + (f & 1)*2 + (l16 >> 3);
          qk[pos*64 + ((c ^ swq) << 3) + (l16 & 7)] = f2b(accA[mi][f][r]);
        }
      }
    }

  // ---- GEMM group B: V (frags 4,5); acc held across barrier 2 (32 VGPR)
  f32x4 accB[4][2];
  #pragma unroll
  for (int mi = 0; mi < 4; ++mi)
    #pragma unroll
    for (int f = 0; f < 2; ++f) accB[mi][f] = f32x4{0.f,0.f,0.f,0.f};

  for (int k = 0; k < 12; ++k) {
    bf16x8 a[4], bb[2];
    #pragma unroll
    for (int mi = 0; mi < 4; ++mi) {
      int row = mi*16 + l16; if (row > 48) row = 48;
      a[mi] = *(const bf16x8*)(At + row*384 + (((k*4 + quad) ^ (row & 7)) << 3));
    }
    #pragma unroll
    for (int f = 0; f < 2; ++f) {
      const int nf = 48 + wv*2 + f;                  // V: 48..71
      bb[f] = *(const bf16x8*)(wqkvp + ((size_t)(nf*12 + k)*64 + lane)*8);
    }
    #pragma unroll
    for (int mi = 0; mi < 4; ++mi)
      #pragma unroll
      for (int f = 0; f < 2; ++f)
        accB[mi][f] = MFMA16(a[mi], bb[f], accB[mi][f]);
  }
  __syncthreads();   // barrier 2: all At reads done -> Vt overlay is safe

  // zero own V^T slot (pos pads), then scatter V^T
  #pragma unroll
  for (int i = 0; i < 4; ++i)
    *(uint4*)(vt + (i*64 + lane)*8) = uint4{0,0,0,0};
  #pragma unroll
  for (int mi = 0; mi < 4; ++mi)
    #pragma unroll
    for (int r = 0; r < 4; ++r) {
      const int pos = mi*16 + quad*4 + r;
      if (pos < 49) {
        #pragma unroll
        for (int f = 0; f < 2; ++f) {
          const int d = f*16 + l16;
          vt[d*64 + (((pos >> 3) ^ (d & 7)) << 3) + (pos & 7)] = f2b(accB[mi][f][r]);
        }
      }
    }

  // ---- QK^T (A: row=q pos, B: col=key pos; clamp pad rows to 48)
  bf16x8 aq[4], bk[4];
  #pragma unroll
  for (int mt = 0; mt < 4; ++mt) {
    int p2 = mt*16 + l16; if (p2 > 48) p2 = 48;
    aq[mt] = *(const bf16x8*)(qk + p2*64 + ((quad ^ ((p2 >> 1) & 7)) << 3));
  }
  #pragma unroll
  for (int n = 0; n < 4; ++n) {
    int kp = n*16 + l16; if (kp > 48) kp = 48;
    bk[n] = *(const bf16x8*)(qk + kp*64 + (((4 + quad) ^ ((kp >> 1) & 7)) << 3));
  }
  f32x4 sc[4][4];
  #pragma unroll
  for (int mt = 0; mt < 4; ++mt)
    #pragma unroll
    for (int n = 0; n < 4; ++n) {
      f32x4 z = {0.f,0.f,0.f,0.f};
      sc[mt][n] = MFMA16(aq[mt], bk[n], z);
    }

  // ---- bias + mask + fixed-shift softmax (exact: softmax shift-invariant;
  // scores are O(1), so exp(s-8) spans ~[e-14, 1] well inside f32 range).
  #pragma unroll
  for (int mt = 0; mt < 4; ++mt)
    #pragma unroll
    for (int r = 0; r < 4; ++r) {
      const int q = mt*16 + quad*4 + r;
      const int qy = q / 7, qx = q - qy*7;
      #pragma unroll
      for (int n = 0; n < 4; ++n) {
        const int key = n*16 + l16;
        float s = sc[mt][n][r] * 0.17677669529663687f;   // 1/sqrt(32)
        if (key < 49 && q < 49) {
          const int ky = key / 7, kx = key - ky*7;
          s += relb[wv][(ky - qy + 6)*13 + (kx - qx + 6)];
          if (hb == 7 && ((qy >= 4) != (ky >= 4))) s = NEGHUGE;  // UL mask
        } else {
          s = NEGHUGE;
        }
        sc[mt][n][r] = s;
      }
      float sum = 0.f;
      #pragma unroll
      for (int n = 0; n < 4; ++n) {
        float p = exp2f((sc[mt][n][r] - 8.0f) * 1.4426950408889634f);
        sc[mt][n][r] = p; sum += p;
      }
      sum += __shfl_xor(sum, 1);
      sum += __shfl_xor(sum, 2);
      sum += __shfl_xor(sum, 4);
      sum += __shfl_xor(sum, 8);
      const float rinv = 1.0f / sum;
      if (q < 49) {
        const int swq = (q >> 1) & 7;
        #pragma unroll
        for (int n = 0; n < 4; ++n)
          qk[q*64 + (((n*2 + (l16 >> 3)) ^ swq) << 3) + (l16 & 7)] =
              f2b(sc[mt][n][r] * rinv);
      }
    }

  // ---- PV -> O overlay in own qk slot (stride-40 rows; per-mt offsets of
  // O writes stay strictly below later-mt P reads -> no WAR hazard)
  #pragma unroll
  for (int mt = 0; mt < 4; ++mt) {
    int rp = mt*16 + l16; if (rp > 48) rp = 48;
    const int swp = (rp >> 1) & 7;
    const bf16x8 ap0 = *(const bf16x8*)(qk + rp*64 + ((quad ^ swp) << 3));
    const bf16x8 ap1 = *(const bf16x8*)(qk + rp*64 + (((4+quad) ^ swp) << 3));
    #pragma unroll
    for (int n2 = 0; n2 < 2; ++n2) {
      const int d = n2*16 + l16;
      const bf16x8 bv0 = *(const bf16x8*)(vt + d*64 + ((quad ^ (d & 7)) << 3));
      const bf16x8 bv1 = *(const bf16x8*)(vt + d*64 + (((4+quad) ^ (d & 7)) << 3));
      f32x4 o = {0.f,0.f,0.f,0.f};
      o = MFMA16(ap0, bv0, o);
      o = MFMA16(ap1, bv1, o);
      #pragma unroll
      for (int r = 0; r < 4; ++r) {
        const int q = mt*16 + quad*4 + r;
        if (q < 49) qk[q*40 + n2*16 + l16] = f2b(o[r]);
      }
    }
  }
  __syncthreads();   // barrier 3: all heads' O ready

  // ---- projection: out = attn @ w_out^T + b_out; k-iter == head;
  // A-frag = 16B contiguous span of O overlay (stride 40 -> 2-way banks)
  f32x4 pacc[4][2];
  #pragma unroll
  for (int mi = 0; mi < 4; ++mi)
    #pragma unroll
    for (int j = 0; j < 2; ++j) pacc[mi][j] = f32x4{0.f,0.f,0.f,0.f};

  for (int k = 0; k < 12; ++k) {
    bf16x8 a[4], bb[2];
    #pragma unroll
    for (int mi = 0; mi < 4; ++mi) {
      int row = mi*16 + l16; if (row > 48) row = 48;
      a[mi] = *(const bf16x8*)(&QKs[k][row*40 + quad*8]);
    }
    #pragma unroll
    for (int j = 0; j < 2; ++j) {
      const int nf = wv*2 + j;
      bb[j] = *(const bf16x8*)(woutp + ((size_t)(nf*12 + k)*64 + lane)*8);
    }
    #pragma unroll
    for (int mi = 0; mi < 4; ++mi)
      #pragma unroll
      for (int j = 0; j < 2; ++j)
        pacc[mi][j] = MFMA16(a[mi], bb[j], pacc[mi][j]);
  }

  float bias[2];
  #pragma unroll
  for (int j = 0; j < 2; ++j) bias[j] = bout[wv*32 + j*16 + l16];

  #pragma unroll
  for (int mi = 0; mi < 4; ++mi)
    #pragma unroll
    for (int r = 0; r < 4; ++r) {
      const int q = mi*16 + quad*4 + r;
      if (q < 49) {
        const int py = q / 7, px = q - py*7;
        int hh = hb*7 + py + 3; if (hh >= 56) hh -= 56;   // inverse roll
        int ww = wb*7 + px + 3; if (ww >= 56) ww -= 56;
        float* dst = out + (size_t)((b*56 + hh)*56 + ww)*384 + wv*32;
        #pragma unroll
        for (int j = 0; j < 2; ++j)
          dst[j*16 + l16] = pacc[mi][j][r] + bias[j];
      }
    }
}

extern "C" void kernel_launch(void* const* d_in, const int* in_sizes, int n_in,
                              void* d_out, int out_size, void* d_ws, size_t ws_size,
                              hipStream_t stream) {
  const float* x    = (const float*)d_in[0];
  const float* wqkv = (const float*)d_in[1];
  const float* wout = (const float*)d_in[2];
  const float* bout = (const float*)d_in[3];
  const float* relt = (const float*)d_in[4];

  char* ws = (char*)d_ws;
  u16* xb    = (u16*)(ws);                        // 38,535,168 B
  u16* wqkvp = (u16*)(ws + 38535168);             //    884,736 B
  u16* woutp = (u16*)(ws + 39419904);             //    294,912 B
  float* outp = (float*)d_out;

  k_convert<<<9696, 256, 0, stream>>>(x, wqkv, wout, xb, wqkvp, woutp);
  k_fused<<<1024, 768, 0, stream>>>(xb, wqkvp, woutp, bout, relt, outp);
}

// Round 8
// 286.734 us; speedup vs baseline: 1.4961x; 1.0008x over previous
//
#include <hip/hip_runtime.h>

typedef unsigned short u16;
typedef short bf16x8 __attribute__((ext_vector_type(8)));
typedef float f32x4 __attribute__((ext_vector_type(4)));

#define MFMA16(a,b,c) __builtin_amdgcn_mfma_f32_16x16x32_bf16((a),(b),(c),0,0,0)
#define NEGHUGE (-1.0e30f)

__device__ __forceinline__ u16 f2b(float f){
  union { float f; unsigned int i; } v; v.f = f;
  unsigned int r = v.i + 0x7FFFu + ((v.i>>16)&1u);
  return (u16)(r>>16);
}

union BfPack { u16 h[8]; bf16x8 v; uint4 u; };

__device__ __forceinline__ uint4 pack8u(const float* __restrict__ p){
  float4 a = *(const float4*)p;
  float4 b = *(const float4*)(p + 4);
  BfPack r;
  r.h[0]=f2b(a.x); r.h[1]=f2b(a.y); r.h[2]=f2b(a.z); r.h[3]=f2b(a.w);
  r.h[4]=f2b(b.x); r.h[5]=f2b(b.y); r.h[6]=f2b(b.z); r.h[7]=f2b(b.w);
  return r.u;
}

// ---------------- kernel 1: weight fragment-packing (f32 -> bf16) ------------
// unit u = (nf*12 + k)*64 + l holds W[nf*16 + (l&15)][k*32 + (l>>4)*8 .. +8].
// wqkv: 55,296 units | wout: 18,432 units; grid 288*256 = 73,728 exact.
__global__ __launch_bounds__(256) void k_convert_w(
    const float* __restrict__ wqkv, const float* __restrict__ wout,
    u16* __restrict__ wqkvp, u16* __restrict__ woutp)
{
  int idx = (int)blockIdx.x * 256 + threadIdx.x;
  const float* W; u16* dst; int u;
  if (idx < 55296) { W = wqkv; dst = wqkvp; u = idx; }
  else             { W = wout; dst = woutp; u = idx - 55296; }
  int nf = u / 768, rem = u - nf*768, k = rem >> 6, l = rem & 63;
  const float* src = W + (size_t)(nf*16 + (l & 15))*384 + k*32 + (l >> 4)*8;
  *(uint4*)(dst + (size_t)u*8) = pack8u(src);
}

// ---------------- kernel 2: fused QKV + attention + projection ---------------
// 1 block = 1 window (1024 blocks), 12 waves (768 thr), wave wv = head wv.
// LDS overlays (132,528 B -> 3 waves/SIMD):
//   R1   49,152 B: x-tile At (bf16, converted in-kernel) ... then Vts[12][2048]
//   QKs  75,264 B: per-head Q|K (49x64) -> P -> O (49x40 overlay)
//   relb  8,112 B
// Spill fix (r7 post-mortem): per-mt fused QK^T -> softmax -> PV pipeline
// (#pragma unroll 1) keeps peak live regs ~75, inside the 170 unified cap.
__global__ __launch_bounds__(768, 3) void k_fused(
    const float* __restrict__ x, const u16* __restrict__ wqkvp,
    const u16* __restrict__ woutp, const float* __restrict__ bout,
    const float* __restrict__ relt, float* __restrict__ out)
{
  __shared__ u16 R1[64*384];        // 49152 B: At, later Vts[12][2048]
  __shared__ u16 QKs[12][49*64];    // 75264 B: per-head Q|K -> P -> O
  __shared__ float relb[12][169];   //  8112 B

  const int tid = threadIdx.x;
  const int wv = tid >> 6, lane = tid & 63, quad = lane >> 4, l16 = lane & 15;
  const int blk = (int)blockIdx.x;                 // 1024 blocks
  const int b = blk >> 6, win = blk & 63, hb = win >> 3, wb = win & 7;

  u16* qk = &QKs[wv][0];
  u16* At = R1;
  u16* vt = R1 + wv*2048;          // valid only after barrier 2

  // rel-pos column for this head (own slot; consumed only by own wave)
  for (int i = lane; i < 169; i += 64) relb[wv][i] = relt[i*12 + wv];

  // stage x-window -> At: 2352 units (49 rows x 48 chunks of 8 floats),
  // reg-staged f32 -> bf16, ds_write at XOR-swizzled chunk (c ^ (r&7))
  #pragma unroll
  for (int i = 0; i < 4; ++i) {
    const int u = i*768 + tid;
    if (u < 2352) {
      const int r = u / 48, c = u - r*48;
      const int py = r / 7, px = r - py*7;
      int hh = hb*7 + py + 3; if (hh >= 56) hh -= 56;
      int ww = wb*7 + px + 3; if (ww >= 56) ww -= 56;
      uint4 v = pack8u(x + (size_t)((b*56 + hh)*56 + ww)*384 + c*8);
      *(uint4*)(At + (size_t)(r*48 + (c ^ (r & 7)))*8) = v;
    }
  }
  __syncthreads();   // barrier 1: At ready

  // ---- GEMM group A: Q,K (frags 0..3) for head wv
  f32x4 accA[4][4];
  #pragma unroll
  for (int mi = 0; mi < 4; ++mi)
    #pragma unroll
    for (int f = 0; f < 4; ++f) accA[mi][f] = f32x4{0.f,0.f,0.f,0.f};

  for (int k = 0; k < 12; ++k) {
    bf16x8 a[4], bb[4];
    #pragma unroll
    for (int mi = 0; mi < 4; ++mi) {
      int row = mi*16 + l16; if (row > 48) row = 48;
      a[mi] = *(const bf16x8*)(At + row*384 + (((k*4 + quad) ^ (row & 7)) << 3));
    }
    #pragma unroll
    for (int f = 0; f < 4; ++f) {
      const int nf = (f >> 1)*24 + wv*2 + (f & 1);   // Q: 0..23, K: 24..47
      bb[f] = *(const bf16x8*)(wqkvp + ((size_t)(nf*12 + k)*64 + lane)*8);
    }
    #pragma unroll
    for (int mi = 0; mi < 4; ++mi)
      #pragma unroll
      for (int f = 0; f < 4; ++f)
        accA[mi][f] = MFMA16(a[mi], bb[f], accA[mi][f]);
  }

  // epilogue A -> qk (Q chunks 0..3, K chunks 4..7), quad-safe swizzle
  #pragma unroll
  for (int mi = 0; mi < 4; ++mi)
    #pragma unroll
    for (int r = 0; r < 4; ++r) {
      const int pos = mi*16 + quad*4 + r;
      if (pos < 49) {
        const int swq = (pos >> 1) & 7;
        #pragma unroll
        for (int f = 0; f < 4; ++f) {
          const int c = (f >> 1)*4 + (f & 1)*2 + (l16 >> 3);
          qk[pos*64 + ((c ^ swq) << 3) + (l16 & 7)] = f2b(accA[mi][f][r]);
        }
      }
    }

  // ---- GEMM group B: V (frags 4,5); acc held across barrier 2 (32 VGPR)
  f32x4 accB[4][2];
  #pragma unroll
  for (int mi = 0; mi < 4; ++mi)
    #pragma unroll
    for (int f = 0; f < 2; ++f) accB[mi][f] = f32x4{0.f,0.f,0.f,0.f};

  for (int k = 0; k < 12; ++k) {
    bf16x8 a[4], bb[2];
    #pragma unroll
    for (int mi = 0; mi < 4; ++mi) {
      int row = mi*16 + l16; if (row > 48) row = 48;
      a[mi] = *(const bf16x8*)(At + row*384 + (((k*4 + quad) ^ (row & 7)) << 3));
    }
    #pragma unroll
    for (int f = 0; f < 2; ++f) {
      const int nf = 48 + wv*2 + f;                  // V: 48..71
      bb[f] = *(const bf16x8*)(wqkvp + ((size_t)(nf*12 + k)*64 + lane)*8);
    }
    #pragma unroll
    for (int mi = 0; mi < 4; ++mi)
      #pragma unroll
      for (int f = 0; f < 2; ++f)
        accB[mi][f] = MFMA16(a[mi], bb[f], accB[mi][f]);
  }
  __syncthreads();   // barrier 2: all At reads done -> Vt overlay is safe

  // zero own V^T slot (pos pads), then scatter V^T
  #pragma unroll
  for (int i = 0; i < 4; ++i)
    *(uint4*)(vt + (i*64 + lane)*8) = uint4{0,0,0,0};
  #pragma unroll
  for (int mi = 0; mi < 4; ++mi)
    #pragma unroll
    for (int r = 0; r < 4; ++r) {
      const int pos = mi*16 + quad*4 + r;
      if (pos < 49) {
        #pragma unroll
        for (int f = 0; f < 2; ++f) {
          const int d = f*16 + l16;
          vt[d*64 + (((pos >> 3) ^ (d & 7)) << 3) + (pos & 7)] = f2b(accB[mi][f][r]);
        }
      }
    }

  // hoist K B-frags and V frags to registers (invariant across mt tiles)
  bf16x8 bkf[4];
  #pragma unroll
  for (int n = 0; n < 4; ++n) {
    int kp = n*16 + l16; if (kp > 48) kp = 48;
    bkf[n] = *(const bf16x8*)(qk + kp*64 + (((4 + quad) ^ ((kp >> 1) & 7)) << 3));
  }
  bf16x8 bv0[2], bv1[2];
  #pragma unroll
  for (int n2 = 0; n2 < 2; ++n2) {
    const int d = n2*16 + l16;
    bv0[n2] = *(const bf16x8*)(vt + d*64 + ((quad ^ (d & 7)) << 3));
    bv1[n2] = *(const bf16x8*)(vt + d*64 + (((4+quad) ^ (d & 7)) << 3));
  }

  // ---- per-mt fused QK^T -> softmax -> PV (low register pressure)
  #pragma unroll 1
  for (int mt = 0; mt < 4; ++mt) {
    int p2 = mt*16 + l16; if (p2 > 48) p2 = 48;
    const bf16x8 aq = *(const bf16x8*)(qk + p2*64 + ((quad ^ ((p2 >> 1) & 7)) << 3));
    f32x4 sc[4];
    #pragma unroll
    for (int n = 0; n < 4; ++n) {
      f32x4 z = {0.f,0.f,0.f,0.f};
      sc[n] = MFMA16(aq, bkf[n], z);
    }

    // bias + mask + fixed-shift softmax (shift-invariant; scores O(1))
    #pragma unroll
    for (int r = 0; r < 4; ++r) {
      const int q = mt*16 + quad*4 + r;
      const int qy = q / 7, qx = q - qy*7;
      #pragma unroll
      for (int n = 0; n < 4; ++n) {
        const int key = n*16 + l16;
        float s = sc[n][r] * 0.17677669529663687f;   // 1/sqrt(32)
        if (key < 49 && q < 49) {
          const int ky = key / 7, kx = key - ky*7;
          s += relb[wv][(ky - qy + 6)*13 + (kx - qx + 6)];
          if (hb == 7 && ((qy >= 4) != (ky >= 4))) s = NEGHUGE;  // UL mask
        } else {
          s = NEGHUGE;
        }
        sc[n][r] = s;
      }
      float sum = 0.f;
      #pragma unroll
      for (int n = 0; n < 4; ++n) {
        float p = exp2f((sc[n][r] - 8.0f) * 1.4426950408889634f);
        sc[n][r] = p; sum += p;
      }
      sum += __shfl_xor(sum, 1);
      sum += __shfl_xor(sum, 2);
      sum += __shfl_xor(sum, 4);
      sum += __shfl_xor(sum, 8);
      const float rinv = 1.0f / sum;
      if (q < 49) {
        const int swq = (q >> 1) & 7;
        #pragma unroll
        for (int n = 0; n < 4; ++n)
          qk[q*64 + (((n*2 + (l16 >> 3)) ^ swq) << 3) + (l16 & 7)] =
              f2b(sc[n][r] * rinv);
      }
    }

    // PV for this mt; O overlay (stride-40) sits below later-mt P rows
    {
      int rp = mt*16 + l16; if (rp > 48) rp = 48;
      const int swp = (rp >> 1) & 7;
      const bf16x8 ap0 = *(const bf16x8*)(qk + rp*64 + ((quad ^ swp) << 3));
      const bf16x8 ap1 = *(const bf16x8*)(qk + rp*64 + (((4+quad) ^ swp) << 3));
      #pragma unroll
      for (int n2 = 0; n2 < 2; ++n2) {
        f32x4 o = {0.f,0.f,0.f,0.f};
        o = MFMA16(ap0, bv0[n2], o);
        o = MFMA16(ap1, bv1[n2], o);
        #pragma unroll
        for (int r = 0; r < 4; ++r) {
          const int q = mt*16 + quad*4 + r;
          if (q < 49) qk[q*40 + n2*16 + l16] = f2b(o[r]);
        }
      }
    }
  }
  __syncthreads();   // barrier 3: all heads' O ready

  // ---- projection: out = attn @ w_out^T + b_out; k-iter == head;
  // A-frag = 16B contiguous span of O overlay (stride 40 -> 2-way banks)
  f32x4 pacc[4][2];
  #pragma unroll
  for (int mi = 0; mi < 4; ++mi)
    #pragma unroll
    for (int j = 0; j < 2; ++j) pacc[mi][j] = f32x4{0.f,0.f,0.f,0.f};

  for (int k = 0; k < 12; ++k) {
    bf16x8 a[4], bb[2];
    #pragma unroll
    for (int mi = 0; mi < 4; ++mi) {
      int row = mi*16 + l16; if (row > 48) row = 48;
      a[mi] = *(const bf16x8*)(&QKs[k][row*40 + quad*8]);
    }
    #pragma unroll
    for (int j = 0; j < 2; ++j) {
      const int nf = wv*2 + j;
      bb[j] = *(const bf16x8*)(woutp + ((size_t)(nf*12 + k)*64 + lane)*8);
    }
    #pragma unroll
    for (int mi = 0; mi < 4; ++mi)
      #pragma unroll
      for (int j = 0; j < 2; ++j)
        pacc[mi][j] = MFMA16(a[mi], bb[j], pacc[mi][j]);
  }

  float bias[2];
  #pragma unroll
  for (int j = 0; j < 2; ++j) bias[j] = bout[wv*32 + j*16 + l16];

  #pragma unroll
  for (int mi = 0; mi < 4; ++mi)
    #pragma unroll
    for (int r = 0; r < 4; ++r) {
      const int q = mi*16 + quad*4 + r;
      if (q < 49) {
        const int py = q / 7, px = q - py*7;
        int hh = hb*7 + py + 3; if (hh >= 56) hh -= 56;   // inverse roll
        int ww = wb*7 + px + 3; if (ww >= 56) ww -= 56;
        float* dst = out + (size_t)((b*56 + hh)*56 + ww)*384 + wv*32;
        #pragma unroll
        for (int j = 0; j < 2; ++j)
          dst[j*16 + l16] = pacc[mi][j][r] + bias[j];
      }
    }
}

extern "C" void kernel_launch(void* const* d_in, const int* in_sizes, int n_in,
                              void* d_out, int out_size, void* d_ws, size_t ws_size,
                              hipStream_t stream) {
  const float* x    = (const float*)d_in[0];
  const float* wqkv = (const float*)d_in[1];
  const float* wout = (const float*)d_in[2];
  const float* bout = (const float*)d_in[3];
  const float* relt = (const float*)d_in[4];

  char* ws = (char*)d_ws;
  u16* wqkvp = (u16*)(ws);                        //    884,736 B
  u16* woutp = (u16*)(ws + 884736);               //    294,912 B
  float* outp = (float*)d_out;

  k_convert_w<<<288, 256, 0, stream>>>(wqkv, wout, wqkvp, woutp);
  k_fused<<<1024, 768, 0, stream>>>(x, wqkvp, woutp, bout, relt, outp);
}

// Round 9
// 283.801 us; speedup vs baseline: 1.5115x; 1.0103x over previous
//
#include <hip/hip_runtime.h>

typedef unsigned short u16;
typedef short bf16x8 __attribute__((ext_vector_type(8)));
typedef float f32x4 __attribute__((ext_vector_type(4)));

#define MFMA16(a,b,c) __builtin_amdgcn_mfma_f32_16x16x32_bf16((a),(b),(c),0,0,0)
#define NEGHUGE (-1.0e30f)

__device__ __forceinline__ u16 f2b(float f){
  union { float f; unsigned int i; } v; v.f = f;
  unsigned int r = v.i + 0x7FFFu + ((v.i>>16)&1u);
  return (u16)(r>>16);
}

union BfPack { u16 h[8]; bf16x8 v; uint4 u; };

__device__ __forceinline__ uint4 pack8u(const float* __restrict__ p){
  float4 a = *(const float4*)p;
  float4 b = *(const float4*)(p + 4);
  BfPack r;
  r.h[0]=f2b(a.x); r.h[1]=f2b(a.y); r.h[2]=f2b(a.z); r.h[3]=f2b(a.w);
  r.h[4]=f2b(b.x); r.h[5]=f2b(b.y); r.h[6]=f2b(b.z); r.h[7]=f2b(b.w);
  return r.u;
}

// ---------------- kernel 1: weight fragment-packing (f32 -> bf16) ------------
// unit u = (nf*12 + k)*64 + l holds W[nf*16 + (l&15)][k*32 + (l>>4)*8 .. +8].
// wqkv: 55,296 units | wout: 18,432 units; grid 288*256 = 73,728 exact.
__global__ __launch_bounds__(256) void k_convert_w(
    const float* __restrict__ wqkv, const float* __restrict__ wout,
    u16* __restrict__ wqkvp, u16* __restrict__ woutp)
{
  int idx = (int)blockIdx.x * 256 + threadIdx.x;
  const float* W; u16* dst; int u;
  if (idx < 55296) { W = wqkv; dst = wqkvp; u = idx; }
  else             { W = wout; dst = woutp; u = idx - 55296; }
  int nf = u / 768, rem = u - nf*768, k = rem >> 6, l = rem & 63;
  const float* src = W + (size_t)(nf*16 + (l & 15))*384 + k*32 + (l >> 4)*8;
  *(uint4*)(dst + (size_t)u*8) = pack8u(src);
}

// ---------------- kernel 2: fused QKV + attention + projection ---------------
// 1 block = 1 window (1024 blocks), 12 waves (768 thr), wave wv = head wv.
// SPILL FIX (r8 post-mortem): no LDS overlays -> no accumulator crosses a
// barrier. Separate regions (162,048 B <= 160 KiB):
//   At  [49][384]    37,632 B  x-window tile (bf16, chunk-XOR swizzled)
//   QKs [12][49*64]  75,264 B  per-head Q|K -> P -> O (stride-40 overlay)
//   Vts [12][32*64]  49,152 B  per-head V^T (zero-padded pos, d-XOR swizzle)
// rel-pos bias: read from global relt (6.8 KB, L1-resident), prefetched
// 16-at-a-time into regs per mt-tile. 2 barriers total.
__global__ __launch_bounds__(768, 3) void k_fused(
    const float* __restrict__ x, const u16* __restrict__ wqkvp,
    const u16* __restrict__ woutp, const float* __restrict__ bout,
    const float* __restrict__ relt, float* __restrict__ out)
{
  __shared__ u16 At[49*384];        // 37,632 B
  __shared__ u16 QKs[12][49*64];    // 75,264 B
  __shared__ u16 Vts[12][32*64];    // 49,152 B

  const int tid = threadIdx.x;
  const int wv = tid >> 6, lane = tid & 63, quad = lane >> 4, l16 = lane & 15;
  const int blk = (int)blockIdx.x;                 // 1024 blocks
  const int b = blk >> 6, win = blk & 63, hb = win >> 3, wb = win & 7;

  u16* qk = &QKs[wv][0];
  u16* vt = &Vts[wv][0];

  // zero own V^T slot (pads pos 49..63 stay zero)
  #pragma unroll
  for (int i = 0; i < 4; ++i)
    *(uint4*)(vt + (i*64 + lane)*8) = uint4{0,0,0,0};

  // stage x-window -> At: 2352 units (49 rows x 48 chunks of 8 floats),
  // reg-staged f32 -> bf16, ds_write at XOR-swizzled chunk (c ^ (r&7))
  #pragma unroll
  for (int i = 0; i < 4; ++i) {
    const int u = i*768 + tid;
    if (u < 2352) {
      const int r = u / 48, c = u - r*48;
      const int py = r / 7, px = r - py*7;
      int hh = hb*7 + py + 3; if (hh >= 56) hh -= 56;
      int ww = wb*7 + px + 3; if (ww >= 56) ww -= 56;
      uint4 v = pack8u(x + (size_t)((b*56 + hh)*56 + ww)*384 + c*8);
      *(uint4*)(At + (size_t)(r*48 + (c ^ (r & 7)))*8) = v;
    }
  }
  __syncthreads();   // barrier 1: At ready

  // ---- GEMM group A: Q,K (frags 0..3) for head wv
  f32x4 accA[4][4];
  #pragma unroll
  for (int mi = 0; mi < 4; ++mi)
    #pragma unroll
    for (int f = 0; f < 4; ++f) accA[mi][f] = f32x4{0.f,0.f,0.f,0.f};

  for (int k = 0; k < 12; ++k) {
    bf16x8 a[4], bb[4];
    #pragma unroll
    for (int mi = 0; mi < 4; ++mi) {
      int row = mi*16 + l16; if (row > 48) row = 48;
      a[mi] = *(const bf16x8*)(At + row*384 + (((k*4 + quad) ^ (row & 7)) << 3));
    }
    #pragma unroll
    for (int f = 0; f < 4; ++f) {
      const int nf = (f >> 1)*24 + wv*2 + (f & 1);   // Q: 0..23, K: 24..47
      bb[f] = *(const bf16x8*)(wqkvp + ((size_t)(nf*12 + k)*64 + lane)*8);
    }
    #pragma unroll
    for (int mi = 0; mi < 4; ++mi)
      #pragma unroll
      for (int f = 0; f < 4; ++f)
        accA[mi][f] = MFMA16(a[mi], bb[f], accA[mi][f]);
  }

  // epilogue A -> qk (Q chunks 0..3, K chunks 4..7), quad-safe swizzle
  #pragma unroll
  for (int mi = 0; mi < 4; ++mi)
    #pragma unroll
    for (int r = 0; r < 4; ++r) {
      const int pos = mi*16 + quad*4 + r;
      if (pos < 49) {
        const int swq = (pos >> 1) & 7;
        #pragma unroll
        for (int f = 0; f < 4; ++f) {
          const int c = (f >> 1)*4 + (f & 1)*2 + (l16 >> 3);
          qk[pos*64 + ((c ^ swq) << 3) + (l16 & 7)] = f2b(accA[mi][f][r]);
        }
      }
    }

  // ---- GEMM group B: V (frags 4,5); epilogue IMMEDIATE (no barrier crossed)
  f32x4 accB[4][2];
  #pragma unroll
  for (int mi = 0; mi < 4; ++mi)
    #pragma unroll
    for (int f = 0; f < 2; ++f) accB[mi][f] = f32x4{0.f,0.f,0.f,0.f};

  for (int k = 0; k < 12; ++k) {
    bf16x8 a[4], bb[2];
    #pragma unroll
    for (int mi = 0; mi < 4; ++mi) {
      int row = mi*16 + l16; if (row > 48) row = 48;
      a[mi] = *(const bf16x8*)(At + row*384 + (((k*4 + quad) ^ (row & 7)) << 3));
    }
    #pragma unroll
    for (int f = 0; f < 2; ++f) {
      const int nf = 48 + wv*2 + f;                  // V: 48..71
      bb[f] = *(const bf16x8*)(wqkvp + ((size_t)(nf*12 + k)*64 + lane)*8);
    }
    #pragma unroll
    for (int mi = 0; mi < 4; ++mi)
      #pragma unroll
      for (int f = 0; f < 2; ++f)
        accB[mi][f] = MFMA16(a[mi], bb[f], accB[mi][f]);
  }

  // V^T scatter to own separate slot (own-wave data, ds ordering suffices)
  #pragma unroll
  for (int mi = 0; mi < 4; ++mi)
    #pragma unroll
    for (int r = 0; r < 4; ++r) {
      const int pos = mi*16 + quad*4 + r;
      if (pos < 49) {
        #pragma unroll
        for (int f = 0; f < 2; ++f) {
          const int d = f*16 + l16;
          vt[d*64 + (((pos >> 3) ^ (d & 7)) << 3) + (pos & 7)] = f2b(accB[mi][f][r]);
        }
      }
    }

  // hoist K B-frags and V frags to registers (invariant across mt tiles)
  bf16x8 bkf[4];
  #pragma unroll
  for (int n = 0; n < 4; ++n) {
    int kp = n*16 + l16; if (kp > 48) kp = 48;
    bkf[n] = *(const bf16x8*)(qk + kp*64 + (((4 + quad) ^ ((kp >> 1) & 7)) << 3));
  }
  bf16x8 bv0[2], bv1[2];
  #pragma unroll
  for (int n2 = 0; n2 < 2; ++n2) {
    const int d = n2*16 + l16;
    bv0[n2] = *(const bf16x8*)(vt + d*64 + ((quad ^ (d & 7)) << 3));
    bv1[n2] = *(const bf16x8*)(vt + d*64 + (((4+quad) ^ (d & 7)) << 3));
  }

  // ---- per-mt fused QK^T -> softmax -> PV (low register pressure)
  #pragma unroll 1
  for (int mt = 0; mt < 4; ++mt) {
    int p2 = mt*16 + l16; if (p2 > 48) p2 = 48;
    const bf16x8 aq = *(const bf16x8*)(qk + p2*64 + ((quad ^ ((p2 >> 1) & 7)) << 3));
    f32x4 sc[4];
    #pragma unroll
    for (int n = 0; n < 4; ++n) {
      f32x4 z = {0.f,0.f,0.f,0.f};
      sc[n] = MFMA16(aq, bkf[n], z);
    }

    // prefetch rel-pos biases for this mt (16 L1-resident scalar loads)
    float rb[4][4];
    #pragma unroll
    for (int r = 0; r < 4; ++r) {
      const int q = mt*16 + quad*4 + r;
      const int qy = q / 7, qx = q - qy*7;
      #pragma unroll
      for (int n = 0; n < 4; ++n) {
        const int key = n*16 + l16;
        int idx = 0;
        if (key < 49 && q < 49) {
          const int ky = key / 7, kx = key - ky*7;
          idx = ((ky - qy + 6)*13 + (kx - qx + 6))*12 + wv;
        }
        rb[r][n] = relt[idx];
      }
    }

    // bias + mask + fixed-shift softmax (shift-invariant; scores O(1))
    #pragma unroll
    for (int r = 0; r < 4; ++r) {
      const int q = mt*16 + quad*4 + r;
      const int qy = q / 7;
      #pragma unroll
      for (int n = 0; n < 4; ++n) {
        const int key = n*16 + l16;
        float s = sc[n][r] * 0.17677669529663687f;   // 1/sqrt(32)
        if (key < 49 && q < 49) {
          const int ky = key / 7;
          s += rb[r][n];
          if (hb == 7 && ((qy >= 4) != (ky >= 4))) s = NEGHUGE;  // UL mask
        } else {
          s = NEGHUGE;
        }
        sc[n][r] = s;
      }
      float sum = 0.f;
      #pragma unroll
      for (int n = 0; n < 4; ++n) {
        float p = exp2f((sc[n][r] - 8.0f) * 1.4426950408889634f);
        sc[n][r] = p; sum += p;
      }
      sum += __shfl_xor(sum, 1);
      sum += __shfl_xor(sum, 2);
      sum += __shfl_xor(sum, 4);
      sum += __shfl_xor(sum, 8);
      const float rinv = 1.0f / sum;
      if (q < 49) {
        const int swq = (q >> 1) & 7;
        #pragma unroll
        for (int n = 0; n < 4; ++n)
          qk[q*64 + (((n*2 + (l16 >> 3)) ^ swq) << 3) + (l16 & 7)] =
              f2b(sc[n][r] * rinv);
      }
    }

    // PV for this mt; O overlay (stride-40) sits below later-mt P rows
    {
      int rp = mt*16 + l16; if (rp > 48) rp = 48;
      const int swp = (rp >> 1) & 7;
      const bf16x8 ap0 = *(const bf16x8*)(qk + rp*64 + ((quad ^ swp) << 3));
      const bf16x8 ap1 = *(const bf16x8*)(qk + rp*64 + (((4+quad) ^ swp) << 3));
      #pragma unroll
      for (int n2 = 0; n2 < 2; ++n2) {
        f32x4 o = {0.f,0.f,0.f,0.f};
        o = MFMA16(ap0, bv0[n2], o);
        o = MFMA16(ap1, bv1[n2], o);
        #pragma unroll
        for (int r = 0; r < 4; ++r) {
          const int q = mt*16 + quad*4 + r;
          if (q < 49) qk[q*40 + n2*16 + l16] = f2b(o[r]);
        }
      }
    }
  }
  __syncthreads();   // barrier 2: all heads' O ready

  // ---- projection: out = attn @ w_out^T + b_out; k-iter == head;
  // A-frag = 16B contiguous span of O overlay (stride 40 -> 2-way banks)
  f32x4 pacc[4][2];
  #pragma unroll
  for (int mi = 0; mi < 4; ++mi)
    #pragma unroll
    for (int j = 0; j < 2; ++j) pacc[mi][j] = f32x4{0.f,0.f,0.f,0.f};

  for (int k = 0; k < 12; ++k) {
    bf16x8 a[4], bb[2];
    #pragma unroll
    for (int mi = 0; mi < 4; ++mi) {
      int row = mi*16 + l16; if (row > 48) row = 48;
      a[mi] = *(const bf16x8*)(&QKs[k][row*40 + quad*8]);
    }
    #pragma unroll
    for (int j = 0; j < 2; ++j) {
      const int nf = wv*2 + j;
      bb[j] = *(const bf16x8*)(woutp + ((size_t)(nf*12 + k)*64 + lane)*8);
    }
    #pragma unroll
    for (int mi = 0; mi < 4; ++mi)
      #pragma unroll
      for (int j = 0; j < 2; ++j)
        pacc[mi][j] = MFMA16(a[mi], bb[j], pacc[mi][j]);
  }

  float bias[2];
  #pragma unroll
  for (int j = 0; j < 2; ++j) bias[j] = bout[wv*32 + j*16 + l16];

  #pragma unroll
  for (int mi = 0; mi < 4; ++mi)
    #pragma unroll
    for (int r = 0; r < 4; ++r) {
      const int q = mi*16 + quad*4 + r;
      if (q < 49) {
        const int py = q / 7, px = q - py*7;
        int hh = hb*7 + py + 3; if (hh >= 56) hh -= 56;   // inverse roll
        int ww = wb*7 + px + 3; if (ww >= 56) ww -= 56;
        float* dst = out + (size_t)((b*56 + hh)*56 + ww)*384 + wv*32;
        #pragma unroll
        for (int j = 0; j < 2; ++j)
          dst[j*16 + l16] = pacc[mi][j][r] + bias[j];
      }
    }
}

extern "C" void kernel_launch(void* const* d_in, const int* in_sizes, int n_in,
                              void* d_out, int out_size, void* d_ws, size_t ws_size,
                              hipStream_t stream) {
  const float* x    = (const float*)d_in[0];
  const float* wqkv = (const float*)d_in[1];
  const float* wout = (const float*)d_in[2];
  const float* bout = (const float*)d_in[3];
  const float* relt = (const float*)d_in[4];

  char* ws = (char*)d_ws;
  u16* wqkvp = (u16*)(ws);                        //    884,736 B
  u16* woutp = (u16*)(ws + 884736);               //    294,912 B
  float* outp = (float*)d_out;

  k_convert_w<<<288, 256, 0, stream>>>(wqkv, wout, wqkvp, woutp);
  k_fused<<<1024, 768, 0, stream>>>(x, wqkvp, woutp, bout, relt, outp);
}